// Round 1
// baseline (801.471 us; speedup 1.0000x reference)
//
#include <hip/hip_runtime.h>
#include <hip/hip_bf16.h>

#define T_TOK 4096
#define H_DIM 2048
#define E_NUM 8
#define I_DIM 1408
#define RTOT  8192   // T_TOK * 2 (top-k rows, always exactly 8192)

typedef __bf16 bf16x8 __attribute__((ext_vector_type(8)));
typedef float  floatx4 __attribute__((ext_vector_type(4)));

__device__ __forceinline__ unsigned short f2bf(float f) {
  union { float f; unsigned u; } v; v.f = f;
  unsigned r = v.u + 0x7FFFu + ((v.u >> 16) & 1u);  // RNE
  return (unsigned short)(r >> 16);
}

__device__ __forceinline__ void async16(const void* g, void* l) {
  __builtin_amdgcn_global_load_lds(
      (__attribute__((address_space(1))) void*)(g),
      (__attribute__((address_space(3))) void*)(l), 16, 0, 0);
}

// ---------------- router: logits -> softmax -> top2 ----------------
__global__ void router_kernel(const float* __restrict__ x, const float* __restrict__ rw,
                              int* __restrict__ topk_idx, float* __restrict__ topk_w,
                              int* __restrict__ counts) {
  int wave = threadIdx.x >> 6, lane = threadIdx.x & 63;
  int t = blockIdx.x * 4 + wave;
  const float* xr = x + (size_t)t * H_DIM;
  float acc[E_NUM];
#pragma unroll
  for (int e = 0; e < E_NUM; e++) acc[e] = 0.f;
  for (int h = lane; h < H_DIM; h += 64) {
    float xv = xr[h];
    const float* wr = rw + h * E_NUM;
#pragma unroll
    for (int e = 0; e < E_NUM; e++) acc[e] += xv * wr[e];
  }
#pragma unroll
  for (int e = 0; e < E_NUM; e++) {
    float v = acc[e];
#pragma unroll
    for (int s = 32; s > 0; s >>= 1) v += __shfl_xor(v, s, 64);
    acc[e] = v;
  }
  if (lane == 0) {
    float mx = acc[0];
#pragma unroll
    for (int e = 1; e < E_NUM; e++) mx = fmaxf(mx, acc[e]);
    float p[E_NUM], s = 0.f;
#pragma unroll
    for (int e = 0; e < E_NUM; e++) { p[e] = __expf(acc[e] - mx); s += p[e]; }
    float inv = 1.0f / s;
    int i0 = 0;
#pragma unroll
    for (int e = 1; e < E_NUM; e++) if (p[e] > p[i0]) i0 = e;
    int i1 = (i0 == 0) ? 1 : 0;
#pragma unroll
    for (int e = 0; e < E_NUM; e++) if (e != i0 && p[e] > p[i1]) i1 = e;
    topk_idx[t * 2]     = i0;
    topk_idx[t * 2 + 1] = i1;
    topk_w[t * 2]       = p[i0] * inv;
    topk_w[t * 2 + 1]   = p[i1] * inv;
    atomicAdd(&counts[i0], 1);
    atomicAdd(&counts[i1], 1);
  }
}

__global__ void scan_kernel(const int* __restrict__ counts, int* __restrict__ offsets,
                            int* __restrict__ cursors) {
  if (threadIdx.x == 0) {
    int o = 0;
    for (int e = 0; e < E_NUM; e++) { offsets[e] = o; cursors[e] = o; o += counts[e]; }
  }
}

__global__ void assign_kernel(const int* __restrict__ topk_idx, int* __restrict__ cursors,
                              int* __restrict__ row_of, int* __restrict__ tok_of) {
  int i = blockIdx.x * blockDim.x + threadIdx.x;  // 0..RTOT-1 = (t,k)
  int e = topk_idx[i];
  int row = atomicAdd(&cursors[e], 1);
  row_of[i] = row;
  tok_of[row] = i >> 1;
}

// gather x rows (fp32) -> permuted bf16 activation matrix Xp (RTOT x H)
__global__ void gather_kernel(const float* __restrict__ x, const int* __restrict__ tok_of,
                              unsigned short* __restrict__ Xp) {
  int row = blockIdx.x;
  int t = tok_of[row];
  const float4* src = (const float4*)(x + (size_t)t * H_DIM);
  ushort4* dst = (ushort4*)(Xp + (size_t)row * H_DIM);
  for (int i = threadIdx.x; i < H_DIM / 4; i += 256) {
    float4 v = src[i];
    ushort4 o;
    o.x = f2bf(v.x); o.y = f2bf(v.y); o.z = f2bf(v.z); o.w = f2bf(v.w);
    dst[i] = o;
  }
}

// ---------------- weight transpose + bf16 cast ----------------
// gate_up (E, H=2048, 2I=2816) fp32 -> WgT (E, I, H), WuT (E, I, H) bf16 (B^T layout)
__global__ void convert_gu_kernel(const float* __restrict__ W,
                                  unsigned short* __restrict__ WgT,
                                  unsigned short* __restrict__ WuT) {
  __shared__ float tile[32][33];
  int e = blockIdx.z;
  int k0 = blockIdx.y * 32;            // over H
  int n0 = blockIdx.x * 32;            // over 2I
  const float* Wp = W + (size_t)e * H_DIM * (2 * I_DIM);
  int tx = threadIdx.x & 31, ty = threadIdx.x >> 5;
#pragma unroll
  for (int i = 0; i < 4; i++) {
    int k = ty + i * 8;
    tile[k][tx] = Wp[(size_t)(k0 + k) * (2 * I_DIM) + n0 + tx];
  }
  __syncthreads();
  unsigned short* Op;
  int nb = n0;
  if (n0 < I_DIM) Op = WgT + (size_t)e * I_DIM * H_DIM;
  else { Op = WuT + (size_t)e * I_DIM * H_DIM; nb = n0 - I_DIM; }
#pragma unroll
  for (int i = 0; i < 4; i++) {
    int n = ty + i * 8;
    Op[(size_t)(nb + n) * H_DIM + k0 + tx] = f2bf(tile[tx][n]);
  }
}

// down (E, I=1408, H=2048) fp32 -> WdT (E, H, I) bf16
__global__ void convert_dn_kernel(const float* __restrict__ W,
                                  unsigned short* __restrict__ WdT) {
  __shared__ float tile[32][33];
  int e = blockIdx.z;
  int k0 = blockIdx.y * 32;            // over I
  int n0 = blockIdx.x * 32;            // over H
  const float* Wp = W + (size_t)e * I_DIM * H_DIM;
  int tx = threadIdx.x & 31, ty = threadIdx.x >> 5;
#pragma unroll
  for (int i = 0; i < 4; i++) {
    int k = ty + i * 8;
    tile[k][tx] = Wp[(size_t)(k0 + k) * H_DIM + n0 + tx];
  }
  __syncthreads();
  unsigned short* Op = WdT + (size_t)e * H_DIM * I_DIM;
#pragma unroll
  for (int i = 0; i < 4; i++) {
    int n = ty + i * 8;
    Op[(size_t)(n0 + n) * I_DIM + k0 + tx] = f2bf(tile[tx][n]);
  }
}

// ---------------- GEMM1: Xp @ [Wg|Wu]^T, fused SiLU*up -> Hmid bf16 ----------------
__global__ __launch_bounds__(256, 2) void gemm1_kernel(
    const unsigned short* __restrict__ Xp,
    const unsigned short* __restrict__ WgT,
    const unsigned short* __restrict__ WuT,
    const int* __restrict__ offsets, const int* __restrict__ counts,
    unsigned short* __restrict__ Hmid) {
  int e = blockIdx.z;
  int cnt = counts[e];
  if ((int)blockIdx.y * 128 >= cnt) return;
  int row_beg = offsets[e];
  int m0 = row_beg + blockIdx.y * 128;
  int row_end = row_beg + cnt;
  int n0 = blockIdx.x * 128;

  __shared__ unsigned short sA[128 * 32];
  __shared__ unsigned short sBg[128 * 32];
  __shared__ unsigned short sBu[128 * 32];

  int tid = threadIdx.x;
  int wave = tid >> 6, lane = tid & 63;

  const unsigned short* ga[2];
  const unsigned short* ggt[2];
  const unsigned short* gut[2];
  unsigned short *la[2], *lg[2], *lu[2];
  const size_t wbase = (size_t)e * I_DIM * H_DIM;
#pragma unroll
  for (int r = 0; r < 2; r++) {
    int lin = r * 256 + tid;
    int row = lin >> 2;
    int col = (lin & 3) * 8;
    int am = m0 + row; if (am > RTOT - 1) am = RTOT - 1;
    ga[r]  = Xp  + (size_t)am * H_DIM + col;
    ggt[r] = WgT + wbase + (size_t)(n0 + row) * H_DIM + col;
    gut[r] = WuT + wbase + (size_t)(n0 + row) * H_DIM + col;
    la[r] = sA  + lin * 8;
    lg[r] = sBg + lin * 8;
    lu[r] = sBu + lin * 8;
  }

  floatx4 accg[4][4] = {};
  floatx4 accu[4][4] = {};

  const unsigned short* sAb = sA  + ((wave & 1) * 64 + (lane & 15)) * 32 + (lane >> 4) * 8;
  const unsigned short* sGb = sBg + ((wave >> 1) * 64 + (lane & 15)) * 32 + (lane >> 4) * 8;
  const unsigned short* sUb = sBu + ((wave >> 1) * 64 + (lane & 15)) * 32 + (lane >> 4) * 8;

  for (int kb = 0; kb < H_DIM / 32; kb++) {
    __syncthreads();
#pragma unroll
    for (int r = 0; r < 2; r++) {
      async16(ga[r],  la[r]); ga[r]  += 32;
      async16(ggt[r], lg[r]); ggt[r] += 32;
      async16(gut[r], lu[r]); gut[r] += 32;
    }
    __syncthreads();
    bf16x8 a[4];
#pragma unroll
    for (int mi = 0; mi < 4; mi++) a[mi] = *(const bf16x8*)(sAb + mi * 16 * 32);
#pragma unroll
    for (int ni = 0; ni < 4; ni++) {
      bf16x8 bg = *(const bf16x8*)(sGb + ni * 16 * 32);
      bf16x8 bu = *(const bf16x8*)(sUb + ni * 16 * 32);
#pragma unroll
      for (int mi = 0; mi < 4; mi++) {
        accg[mi][ni] = __builtin_amdgcn_mfma_f32_16x16x32_bf16(a[mi], bg, accg[mi][ni], 0, 0, 0);
        accu[mi][ni] = __builtin_amdgcn_mfma_f32_16x16x32_bf16(a[mi], bu, accu[mi][ni], 0, 0, 0);
      }
    }
  }

  int mrow = m0 + (wave & 1) * 64 + (lane >> 4) * 4;
  int ncol = n0 + (wave >> 1) * 64 + (lane & 15);
#pragma unroll
  for (int mi = 0; mi < 4; mi++) {
#pragma unroll
    for (int r = 0; r < 4; r++) {
      int m = mrow + mi * 16 + r;
      if (m < row_end) {
        size_t base = (size_t)m * I_DIM + ncol;
#pragma unroll
        for (int ni = 0; ni < 4; ni++) {
          float g = accg[mi][ni][r];
          float u = accu[mi][ni][r];
          float s = g / (1.0f + __expf(-g));
          Hmid[base + ni * 16] = f2bf(s * u);
        }
      }
    }
  }
}

// ---------------- GEMM2: Hmid @ Wd^T -> H2 fp32 ----------------
__global__ __launch_bounds__(256, 2) void gemm2_kernel(
    const unsigned short* __restrict__ Hmid,
    const unsigned short* __restrict__ WdT,
    const int* __restrict__ offsets, const int* __restrict__ counts,
    float* __restrict__ H2) {
  int e = blockIdx.z;
  int cnt = counts[e];
  if ((int)blockIdx.y * 128 >= cnt) return;
  int row_beg = offsets[e];
  int m0 = row_beg + blockIdx.y * 128;
  int row_end = row_beg + cnt;
  int n0 = blockIdx.x * 128;

  __shared__ unsigned short sA[128 * 32];
  __shared__ unsigned short sB[128 * 32];

  int tid = threadIdx.x;
  int wave = tid >> 6, lane = tid & 63;

  const unsigned short* ga[2];
  const unsigned short* gb[2];
  unsigned short *la[2], *lb[2];
  const size_t wbase = (size_t)e * H_DIM * I_DIM;
#pragma unroll
  for (int r = 0; r < 2; r++) {
    int lin = r * 256 + tid;
    int row = lin >> 2;
    int col = (lin & 3) * 8;
    int am = m0 + row; if (am > RTOT - 1) am = RTOT - 1;
    ga[r] = Hmid + (size_t)am * I_DIM + col;
    gb[r] = WdT + wbase + (size_t)(n0 + row) * I_DIM + col;
    la[r] = sA + lin * 8;
    lb[r] = sB + lin * 8;
  }

  floatx4 acc[4][4] = {};

  const unsigned short* sAb = sA + ((wave & 1) * 64 + (lane & 15)) * 32 + (lane >> 4) * 8;
  const unsigned short* sBb = sB + ((wave >> 1) * 64 + (lane & 15)) * 32 + (lane >> 4) * 8;

  for (int kb = 0; kb < I_DIM / 32; kb++) {
    __syncthreads();
#pragma unroll
    for (int r = 0; r < 2; r++) {
      async16(ga[r], la[r]); ga[r] += 32;
      async16(gb[r], lb[r]); gb[r] += 32;
    }
    __syncthreads();
    bf16x8 a[4];
#pragma unroll
    for (int mi = 0; mi < 4; mi++) a[mi] = *(const bf16x8*)(sAb + mi * 16 * 32);
#pragma unroll
    for (int ni = 0; ni < 4; ni++) {
      bf16x8 b = *(const bf16x8*)(sBb + ni * 16 * 32);
#pragma unroll
      for (int mi = 0; mi < 4; mi++)
        acc[mi][ni] = __builtin_amdgcn_mfma_f32_16x16x32_bf16(a[mi], b, acc[mi][ni], 0, 0, 0);
    }
  }

  int mrow = m0 + (wave & 1) * 64 + (lane >> 4) * 4;
  int ncol = n0 + (wave >> 1) * 64 + (lane & 15);
#pragma unroll
  for (int mi = 0; mi < 4; mi++) {
#pragma unroll
    for (int r = 0; r < 4; r++) {
      int m = mrow + mi * 16 + r;
      if (m < row_end) {
        size_t base = (size_t)m * H_DIM + ncol;
#pragma unroll
        for (int ni = 0; ni < 4; ni++) H2[base + ni * 16] = acc[mi][ni][r];
      }
    }
  }
}

// ---------------- combine: out[t] = w0*H2[r0] + w1*H2[r1] ----------------
__global__ void combine_kernel(const float* __restrict__ H2, const int* __restrict__ row_of,
                               const float* __restrict__ topk_w, float* __restrict__ out) {
  int t = blockIdx.x >> 1;
  int part = blockIdx.x & 1;
  int c = part * 1024 + threadIdx.x * 4;
  int r0 = row_of[t * 2], r1 = row_of[t * 2 + 1];
  float w0 = topk_w[t * 2], w1 = topk_w[t * 2 + 1];
  float4 a = *(const float4*)(H2 + (size_t)r0 * H_DIM + c);
  float4 b = *(const float4*)(H2 + (size_t)r1 * H_DIM + c);
  float4 o;
  o.x = w0 * a.x + w1 * b.x;
  o.y = w0 * a.y + w1 * b.y;
  o.z = w0 * a.z + w1 * b.z;
  o.w = w0 * a.w + w1 * b.w;
  *(float4*)(out + (size_t)t * H_DIM + c) = o;
}

extern "C" void kernel_launch(void* const* d_in, const int* in_sizes, int n_in,
                              void* d_out, int out_size, void* d_ws, size_t ws_size,
                              hipStream_t stream) {
  const float* x   = (const float*)d_in[0];
  const float* rw  = (const float*)d_in[1];
  const float* wgu = (const float*)d_in[2];
  const float* wdn = (const float*)d_in[3];
  float* out = (float*)d_out;

  char* ws = (char*)d_ws;
  size_t off = 0;
  auto alloc = [&](size_t b) {
    char* p = ws + off;
    off = (off + b + 255) & ~(size_t)255;
    return p;
  };
  unsigned short* WgT  = (unsigned short*)alloc((size_t)E_NUM * I_DIM * H_DIM * 2);
  unsigned short* WuT  = (unsigned short*)alloc((size_t)E_NUM * I_DIM * H_DIM * 2);
  unsigned short* WdT  = (unsigned short*)alloc((size_t)E_NUM * H_DIM * I_DIM * 2);
  unsigned short* Xp   = (unsigned short*)alloc((size_t)RTOT * H_DIM * 2);
  unsigned short* Hmid = (unsigned short*)alloc((size_t)RTOT * I_DIM * 2);
  float* H2            = (float*)alloc((size_t)RTOT * H_DIM * 4);
  int*   topk_idx      = (int*)alloc(RTOT * 4);
  float* topk_w        = (float*)alloc(RTOT * 4);
  int*   row_of        = (int*)alloc(RTOT * 4);
  int*   tok_of        = (int*)alloc(RTOT * 4);
  int*   counts        = (int*)alloc(256);
  int*   offsets       = (int*)alloc(256);
  int*   cursors       = (int*)alloc(256);

  hipMemsetAsync(counts, 0, E_NUM * sizeof(int), stream);

  convert_gu_kernel<<<dim3(88, 64, 8), 256, 0, stream>>>(wgu, WgT, WuT);
  convert_dn_kernel<<<dim3(64, 44, 8), 256, 0, stream>>>(wdn, WdT);
  router_kernel<<<T_TOK / 4, 256, 0, stream>>>(x, rw, topk_idx, topk_w, counts);
  scan_kernel<<<1, 64, 0, stream>>>(counts, offsets, cursors);
  assign_kernel<<<RTOT / 256, 256, 0, stream>>>(topk_idx, cursors, row_of, tok_of);
  gather_kernel<<<RTOT, 256, 0, stream>>>(x, tok_of, Xp);
  gemm1_kernel<<<dim3(11, 64, 8), 256, 0, stream>>>(Xp, WgT, WuT, offsets, counts, Hmid);
  gemm2_kernel<<<dim3(16, 64, 8), 256, 0, stream>>>(Hmid, WdT, offsets, counts, H2);
  combine_kernel<<<T_TOK * 2, 256, 0, stream>>>(H2, row_of, topk_w, out);
}

// Round 2
// 789.132 us; speedup vs baseline: 1.0156x; 1.0156x over previous
//
#include <hip/hip_runtime.h>
#include <hip/hip_bf16.h>

#define T_TOK 4096
#define H_DIM 2048
#define E_NUM 8
#define I_DIM 1408
#define RTOT  8192   // T_TOK * 2
#define MAXTILES 72  // max M-tiles of 128: 64 + 8 partials

typedef __bf16 bf16x8 __attribute__((ext_vector_type(8)));
typedef float  floatx4 __attribute__((ext_vector_type(4)));

__device__ __forceinline__ unsigned short f2bf(float f) {
  union { float f; unsigned u; } v; v.f = f;
  unsigned r = v.u + 0x7FFFu + ((v.u >> 16) & 1u);  // RNE
  return (unsigned short)(r >> 16);
}

__device__ __forceinline__ void async16(const void* g, void* l) {
  __builtin_amdgcn_global_load_lds(
      (__attribute__((address_space(1))) void*)(g),
      (__attribute__((address_space(3))) void*)(l), 16, 0, 0);
}

// ---------------- router ----------------
__global__ void router_kernel(const float* __restrict__ x, const float* __restrict__ rw,
                              int* __restrict__ topk_idx, float* __restrict__ topk_w,
                              int* __restrict__ counts) {
  int wave = threadIdx.x >> 6, lane = threadIdx.x & 63;
  int t = blockIdx.x * 4 + wave;
  const float* xr = x + (size_t)t * H_DIM;
  float acc[E_NUM];
#pragma unroll
  for (int e = 0; e < E_NUM; e++) acc[e] = 0.f;
  for (int h = lane; h < H_DIM; h += 64) {
    float xv = xr[h];
    const float* wr = rw + h * E_NUM;
#pragma unroll
    for (int e = 0; e < E_NUM; e++) acc[e] += xv * wr[e];
  }
#pragma unroll
  for (int e = 0; e < E_NUM; e++) {
    float v = acc[e];
#pragma unroll
    for (int s = 32; s > 0; s >>= 1) v += __shfl_xor(v, s, 64);
    acc[e] = v;
  }
  if (lane == 0) {
    float mx = acc[0];
#pragma unroll
    for (int e = 1; e < E_NUM; e++) mx = fmaxf(mx, acc[e]);
    float p[E_NUM], s = 0.f;
#pragma unroll
    for (int e = 0; e < E_NUM; e++) { p[e] = __expf(acc[e] - mx); s += p[e]; }
    float inv = 1.0f / s;
    int i0 = 0;
#pragma unroll
    for (int e = 1; e < E_NUM; e++) if (p[e] > p[i0]) i0 = e;
    int i1 = (i0 == 0) ? 1 : 0;
#pragma unroll
    for (int e = 0; e < E_NUM; e++) if (e != i0 && p[e] > p[i1]) i1 = e;
    topk_idx[t * 2]     = i0;
    topk_idx[t * 2 + 1] = i1;
    topk_w[t * 2]       = p[i0] * inv;
    topk_w[t * 2 + 1]   = p[i1] * inv;
    atomicAdd(&counts[i0], 1);
    atomicAdd(&counts[i1], 1);
  }
}

// scan + build exact M-tile table (expert-sorted, contiguous)
__global__ void scan_kernel(const int* __restrict__ counts, int* __restrict__ offsets,
                            int* __restrict__ cursors, int* __restrict__ tile_e,
                            int* __restrict__ tile_m0, int* __restrict__ tile_end) {
  if (threadIdx.x == 0) {
    int o = 0, nt = 0;
    for (int e = 0; e < E_NUM; e++) {
      offsets[e] = o; cursors[e] = o;
      int c = counts[e];
      for (int m = 0; m < c; m += 128) {
        tile_e[nt] = e; tile_m0[nt] = o + m; tile_end[nt] = o + c; nt++;
      }
      o += c;
    }
    for (; nt < MAXTILES; nt++) tile_e[nt] = -1;
  }
}

__global__ void assign_kernel(const int* __restrict__ topk_idx, const float* __restrict__ topk_w,
                              int* __restrict__ cursors, int* __restrict__ row_of,
                              int* __restrict__ tok_of, float* __restrict__ w_of) {
  int i = blockIdx.x * blockDim.x + threadIdx.x;
  int e = topk_idx[i];
  int row = atomicAdd(&cursors[e], 1);
  row_of[i] = row;
  tok_of[row] = i >> 1;
  w_of[row] = topk_w[i];
}

__global__ void gather_kernel(const float* __restrict__ x, const int* __restrict__ tok_of,
                              unsigned short* __restrict__ Xp) {
  int row = blockIdx.x;
  int t = tok_of[row];
  const float4* src = (const float4*)(x + (size_t)t * H_DIM);
  ushort4* dst = (ushort4*)(Xp + (size_t)row * H_DIM);
  for (int i = threadIdx.x; i < H_DIM / 4; i += 256) {
    float4 v = src[i];
    ushort4 o;
    o.x = f2bf(v.x); o.y = f2bf(v.y); o.z = f2bf(v.z); o.w = f2bf(v.w);
    dst[i] = o;
  }
}

// ---------------- weight transpose + bf16 cast ----------------
__global__ void convert_gu_kernel(const float* __restrict__ W,
                                  unsigned short* __restrict__ WgT,
                                  unsigned short* __restrict__ WuT) {
  __shared__ float tile[32][33];
  int e = blockIdx.z;
  int k0 = blockIdx.y * 32;
  int n0 = blockIdx.x * 32;
  const float* Wp = W + (size_t)e * H_DIM * (2 * I_DIM);
  int tx = threadIdx.x & 31, ty = threadIdx.x >> 5;
#pragma unroll
  for (int i = 0; i < 4; i++) {
    int k = ty + i * 8;
    tile[k][tx] = Wp[(size_t)(k0 + k) * (2 * I_DIM) + n0 + tx];
  }
  __syncthreads();
  unsigned short* Op;
  int nb = n0;
  if (n0 < I_DIM) Op = WgT + (size_t)e * I_DIM * H_DIM;
  else { Op = WuT + (size_t)e * I_DIM * H_DIM; nb = n0 - I_DIM; }
#pragma unroll
  for (int i = 0; i < 4; i++) {
    int n = ty + i * 8;
    Op[(size_t)(nb + n) * H_DIM + k0 + tx] = f2bf(tile[tx][n]);
  }
}

__global__ void convert_dn_kernel(const float* __restrict__ W,
                                  unsigned short* __restrict__ WdT) {
  __shared__ float tile[32][33];
  int e = blockIdx.z;
  int k0 = blockIdx.y * 32;
  int n0 = blockIdx.x * 32;
  const float* Wp = W + (size_t)e * I_DIM * H_DIM;
  int tx = threadIdx.x & 31, ty = threadIdx.x >> 5;
#pragma unroll
  for (int i = 0; i < 4; i++) {
    int k = ty + i * 8;
    tile[k][tx] = Wp[(size_t)(k0 + k) * H_DIM + n0 + tx];
  }
  __syncthreads();
  unsigned short* Op = WdT + (size_t)e * H_DIM * I_DIM;
#pragma unroll
  for (int i = 0; i < 4; i++) {
    int n = ty + i * 8;
    Op[(size_t)(n0 + n) * I_DIM + k0 + tx] = f2bf(tile[tx][n]);
  }
}

// ---------------- GEMM1: Xp @ [Wg|Wu]^T, fused SiLU*up -> Hmid bf16 ----------------
// 1-D grid 792 = 8 XCDs * (9 M-tiles * 11 N). XCD-aware swizzle: bid%8 = XCD,
// per-XCD order: chunks of 4 M-tiles, N outer, M inner -> L2 working set
// ~2MB A + shared B tiles.
__global__ __launch_bounds__(256, 2) void gemm1_kernel(
    const unsigned short* __restrict__ Xp,
    const unsigned short* __restrict__ WgT,
    const unsigned short* __restrict__ WuT,
    const int* __restrict__ tile_e, const int* __restrict__ tile_m0,
    const int* __restrict__ tile_end,
    unsigned short* __restrict__ Hmid) {
  int bid = blockIdx.x;
  int xcd = bid & 7, j = bid >> 3;       // j in [0,99)
  int mt, n;
  if (j < 88) {
    int c = j / 44, jj = j % 44;
    n = jj >> 2;
    mt = xcd * 9 + c * 4 + (jj & 3);
  } else {
    mt = xcd * 9 + 8;
    n = j - 88;
  }
  int e = tile_e[mt];
  if (e < 0) return;
  int m0 = tile_m0[mt];
  int row_end = tile_end[mt];
  int n0 = n * 128;

  __shared__ unsigned short sA[128 * 32];
  __shared__ unsigned short sBg[128 * 32];
  __shared__ unsigned short sBu[128 * 32];

  int tid = threadIdx.x;
  int wave = tid >> 6, lane = tid & 63;

  const unsigned short* ga[2];
  const unsigned short* ggt[2];
  const unsigned short* gut[2];
  unsigned short *la[2], *lg[2], *lu[2];
  const size_t wbase = (size_t)e * I_DIM * H_DIM;
#pragma unroll
  for (int r = 0; r < 2; r++) {
    int lin = r * 256 + tid;
    int row = lin >> 2;
    int col = (lin & 3) * 8;
    int am = m0 + row; if (am > RTOT - 1) am = RTOT - 1;
    ga[r]  = Xp  + (size_t)am * H_DIM + col;
    ggt[r] = WgT + wbase + (size_t)(n0 + row) * H_DIM + col;
    gut[r] = WuT + wbase + (size_t)(n0 + row) * H_DIM + col;
    la[r] = sA  + lin * 8;
    lg[r] = sBg + lin * 8;
    lu[r] = sBu + lin * 8;
  }

  floatx4 accg[4][4] = {};
  floatx4 accu[4][4] = {};

  const unsigned short* sAb = sA  + ((wave & 1) * 64 + (lane & 15)) * 32 + (lane >> 4) * 8;
  const unsigned short* sGb = sBg + ((wave >> 1) * 64 + (lane & 15)) * 32 + (lane >> 4) * 8;
  const unsigned short* sUb = sBu + ((wave >> 1) * 64 + (lane & 15)) * 32 + (lane >> 4) * 8;

  for (int kb = 0; kb < H_DIM / 32; kb++) {
    __syncthreads();
#pragma unroll
    for (int r = 0; r < 2; r++) {
      async16(ga[r],  la[r]); ga[r]  += 32;
      async16(ggt[r], lg[r]); ggt[r] += 32;
      async16(gut[r], lu[r]); gut[r] += 32;
    }
    __syncthreads();
    bf16x8 a[4];
#pragma unroll
    for (int mi = 0; mi < 4; mi++) a[mi] = *(const bf16x8*)(sAb + mi * 16 * 32);
#pragma unroll
    for (int ni = 0; ni < 4; ni++) {
      bf16x8 bg = *(const bf16x8*)(sGb + ni * 16 * 32);
      bf16x8 bu = *(const bf16x8*)(sUb + ni * 16 * 32);
#pragma unroll
      for (int mi = 0; mi < 4; mi++) {
        accg[mi][ni] = __builtin_amdgcn_mfma_f32_16x16x32_bf16(a[mi], bg, accg[mi][ni], 0, 0, 0);
        accu[mi][ni] = __builtin_amdgcn_mfma_f32_16x16x32_bf16(a[mi], bu, accu[mi][ni], 0, 0, 0);
      }
    }
  }

  int mrow = m0 + (wave & 1) * 64 + (lane >> 4) * 4;
  int ncol = n0 + (wave >> 1) * 64 + (lane & 15);
#pragma unroll
  for (int mi = 0; mi < 4; mi++) {
#pragma unroll
    for (int r = 0; r < 4; r++) {
      int m = mrow + mi * 16 + r;
      if (m < row_end) {
        size_t base = (size_t)m * I_DIM + ncol;
#pragma unroll
        for (int ni = 0; ni < 4; ni++) {
          float g = accg[mi][ni][r];
          float u = accu[mi][ni][r];
          float s = g / (1.0f + __expf(-g));
          Hmid[base + ni * 16] = f2bf(s * u);
        }
      }
    }
  }
}

// ---------------- GEMM2: Hmid @ Wd^T, fused weighted scatter-add -> out ----------------
// 1-D grid 1152 = 8 XCDs * (9 M-tiles * 16 N).
__global__ __launch_bounds__(256, 2) void gemm2_kernel(
    const unsigned short* __restrict__ Hmid,
    const unsigned short* __restrict__ WdT,
    const int* __restrict__ tile_e, const int* __restrict__ tile_m0,
    const int* __restrict__ tile_end,
    const int* __restrict__ tok_of, const float* __restrict__ w_of,
    float* __restrict__ out) {
  int bid = blockIdx.x;
  int xcd = bid & 7, j = bid >> 3;       // j in [0,144)
  int mt, n;
  if (j < 128) {
    int c = j / 64, jj = j % 64;
    n = jj >> 2;
    mt = xcd * 9 + c * 4 + (jj & 3);
  } else {
    mt = xcd * 9 + 8;
    n = j - 128;
  }
  int e = tile_e[mt];
  if (e < 0) return;
  int m0 = tile_m0[mt];
  int row_end = tile_end[mt];
  int n0 = n * 128;

  __shared__ unsigned short sA[128 * 32];
  __shared__ unsigned short sB[128 * 32];

  int tid = threadIdx.x;
  int wave = tid >> 6, lane = tid & 63;

  const unsigned short* ga[2];
  const unsigned short* gb[2];
  unsigned short *la[2], *lb[2];
  const size_t wbase = (size_t)e * H_DIM * I_DIM;
#pragma unroll
  for (int r = 0; r < 2; r++) {
    int lin = r * 256 + tid;
    int row = lin >> 2;
    int col = (lin & 3) * 8;
    int am = m0 + row; if (am > RTOT - 1) am = RTOT - 1;
    ga[r] = Hmid + (size_t)am * I_DIM + col;
    gb[r] = WdT + wbase + (size_t)(n0 + row) * I_DIM + col;
    la[r] = sA + lin * 8;
    lb[r] = sB + lin * 8;
  }

  floatx4 acc[4][4] = {};

  const unsigned short* sAb = sA + ((wave & 1) * 64 + (lane & 15)) * 32 + (lane >> 4) * 8;
  const unsigned short* sBb = sB + ((wave >> 1) * 64 + (lane & 15)) * 32 + (lane >> 4) * 8;

  for (int kb = 0; kb < I_DIM / 32; kb++) {
    __syncthreads();
#pragma unroll
    for (int r = 0; r < 2; r++) {
      async16(ga[r], la[r]); ga[r] += 32;
      async16(gb[r], lb[r]); gb[r] += 32;
    }
    __syncthreads();
    bf16x8 a[4];
#pragma unroll
    for (int mi = 0; mi < 4; mi++) a[mi] = *(const bf16x8*)(sAb + mi * 16 * 32);
#pragma unroll
    for (int ni = 0; ni < 4; ni++) {
      bf16x8 b = *(const bf16x8*)(sBb + ni * 16 * 32);
#pragma unroll
      for (int mi = 0; mi < 4; mi++)
        acc[mi][ni] = __builtin_amdgcn_mfma_f32_16x16x32_bf16(a[mi], b, acc[mi][ni], 0, 0, 0);
    }
  }

  int mrow = m0 + (wave & 1) * 64 + (lane >> 4) * 4;
  int ncol = n0 + (wave >> 1) * 64 + (lane & 15);
#pragma unroll
  for (int mi = 0; mi < 4; mi++) {
#pragma unroll
    for (int r = 0; r < 4; r++) {
      int m = mrow + mi * 16 + r;
      if (m < row_end) {
        int t = tok_of[m];
        float w = w_of[m];
        float* op = out + (size_t)t * H_DIM + ncol;
#pragma unroll
        for (int ni = 0; ni < 4; ni++)
          atomicAdd(op + ni * 16, w * acc[mi][ni][r]);
      }
    }
  }
}

extern "C" void kernel_launch(void* const* d_in, const int* in_sizes, int n_in,
                              void* d_out, int out_size, void* d_ws, size_t ws_size,
                              hipStream_t stream) {
  const float* x   = (const float*)d_in[0];
  const float* rw  = (const float*)d_in[1];
  const float* wgu = (const float*)d_in[2];
  const float* wdn = (const float*)d_in[3];
  float* out = (float*)d_out;

  char* ws = (char*)d_ws;
  size_t off = 0;
  auto alloc = [&](size_t b) {
    char* p = ws + off;
    off = (off + b + 255) & ~(size_t)255;
    return p;
  };
  unsigned short* WgT  = (unsigned short*)alloc((size_t)E_NUM * I_DIM * H_DIM * 2);
  unsigned short* WuT  = (unsigned short*)alloc((size_t)E_NUM * I_DIM * H_DIM * 2);
  unsigned short* WdT  = (unsigned short*)alloc((size_t)E_NUM * H_DIM * I_DIM * 2);
  unsigned short* Xp   = (unsigned short*)alloc((size_t)RTOT * H_DIM * 2);
  unsigned short* Hmid = (unsigned short*)alloc((size_t)RTOT * I_DIM * 2);
  int*   topk_idx      = (int*)alloc(RTOT * 4);
  float* topk_w        = (float*)alloc(RTOT * 4);
  int*   row_of        = (int*)alloc(RTOT * 4);
  int*   tok_of        = (int*)alloc(RTOT * 4);
  float* w_of          = (float*)alloc(RTOT * 4);
  int*   counts        = (int*)alloc(256);
  int*   offsets       = (int*)alloc(256);
  int*   cursors       = (int*)alloc(256);
  int*   tile_e        = (int*)alloc(128 * 4);
  int*   tile_m0       = (int*)alloc(128 * 4);
  int*   tile_end      = (int*)alloc(128 * 4);

  hipMemsetAsync(counts, 0, E_NUM * sizeof(int), stream);
  hipMemsetAsync(d_out, 0, (size_t)out_size * sizeof(float), stream);

  convert_gu_kernel<<<dim3(88, 64, 8), 256, 0, stream>>>(wgu, WgT, WuT);
  convert_dn_kernel<<<dim3(64, 44, 8), 256, 0, stream>>>(wdn, WdT);
  router_kernel<<<T_TOK / 4, 256, 0, stream>>>(x, rw, topk_idx, topk_w, counts);
  scan_kernel<<<1, 64, 0, stream>>>(counts, offsets, cursors, tile_e, tile_m0, tile_end);
  assign_kernel<<<RTOT / 256, 256, 0, stream>>>(topk_idx, topk_w, cursors, row_of, tok_of, w_of);
  gather_kernel<<<RTOT, 256, 0, stream>>>(x, tok_of, Xp);
  gemm1_kernel<<<8 * 9 * 11, 256, 0, stream>>>(Xp, WgT, WuT, tile_e, tile_m0, tile_end, Hmid);
  gemm2_kernel<<<8 * 9 * 16, 256, 0, stream>>>(Hmid, WdT, tile_e, tile_m0, tile_end, tok_of, w_of, out);
}

// Round 3
// 777.151 us; speedup vs baseline: 1.0313x; 1.0154x over previous
//
#include <hip/hip_runtime.h>
#include <hip/hip_bf16.h>

#define T_TOK 4096
#define H_DIM 2048
#define E_NUM 8
#define I_DIM 1408
#define RTOT  8192   // T_TOK * 2
#define MAXTILES 72  // max M-tiles of 128: 64 + 8 partials

typedef __bf16 bf16x8 __attribute__((ext_vector_type(8)));
typedef float  floatx4 __attribute__((ext_vector_type(4)));

__device__ __forceinline__ unsigned short f2bf(float f) {
  union { float f; unsigned u; } v; v.f = f;
  unsigned r = v.u + 0x7FFFu + ((v.u >> 16) & 1u);  // RNE
  return (unsigned short)(r >> 16);
}

__device__ __forceinline__ void async16(const void* g, void* l) {
  __builtin_amdgcn_global_load_lds(
      (__attribute__((address_space(1))) void*)(g),
      (__attribute__((address_space(3))) void*)(l), 16, 0, 0);
}

// ---------------- router ----------------
__global__ void router_kernel(const float* __restrict__ x, const float* __restrict__ rw,
                              int* __restrict__ topk_idx, float* __restrict__ topk_w,
                              int* __restrict__ counts) {
  int wave = threadIdx.x >> 6, lane = threadIdx.x & 63;
  int t = blockIdx.x * 4 + wave;
  const float* xr = x + (size_t)t * H_DIM;
  float acc[E_NUM];
#pragma unroll
  for (int e = 0; e < E_NUM; e++) acc[e] = 0.f;
  for (int h = lane; h < H_DIM; h += 64) {
    float xv = xr[h];
    const float* wr = rw + h * E_NUM;
#pragma unroll
    for (int e = 0; e < E_NUM; e++) acc[e] += xv * wr[e];
  }
#pragma unroll
  for (int e = 0; e < E_NUM; e++) {
    float v = acc[e];
#pragma unroll
    for (int s = 32; s > 0; s >>= 1) v += __shfl_xor(v, s, 64);
    acc[e] = v;
  }
  if (lane == 0) {
    float mx = acc[0];
#pragma unroll
    for (int e = 1; e < E_NUM; e++) mx = fmaxf(mx, acc[e]);
    float p[E_NUM], s = 0.f;
#pragma unroll
    for (int e = 0; e < E_NUM; e++) { p[e] = __expf(acc[e] - mx); s += p[e]; }
    float inv = 1.0f / s;
    int i0 = 0;
#pragma unroll
    for (int e = 1; e < E_NUM; e++) if (p[e] > p[i0]) i0 = e;
    int i1 = (i0 == 0) ? 1 : 0;
#pragma unroll
    for (int e = 0; e < E_NUM; e++) if (e != i0 && p[e] > p[i1]) i1 = e;
    topk_idx[t * 2]     = i0;
    topk_idx[t * 2 + 1] = i1;
    topk_w[t * 2]       = p[i0] * inv;
    topk_w[t * 2 + 1]   = p[i1] * inv;
    atomicAdd(&counts[i0], 1);
    atomicAdd(&counts[i1], 1);
  }
}

// scan + build exact M-tile table (expert-sorted, contiguous)
__global__ void scan_kernel(const int* __restrict__ counts, int* __restrict__ offsets,
                            int* __restrict__ cursors, int* __restrict__ tile_e,
                            int* __restrict__ tile_m0, int* __restrict__ tile_end) {
  if (threadIdx.x == 0) {
    int o = 0, nt = 0;
    for (int e = 0; e < E_NUM; e++) {
      offsets[e] = o; cursors[e] = o;
      int c = counts[e];
      for (int m = 0; m < c; m += 128) {
        tile_e[nt] = e; tile_m0[nt] = o + m; tile_end[nt] = o + c; nt++;
      }
      o += c;
    }
    for (; nt < MAXTILES; nt++) tile_e[nt] = -1;
  }
}

__global__ void assign_kernel(const int* __restrict__ topk_idx, int* __restrict__ cursors,
                              int* __restrict__ row_of, int* __restrict__ tok_of) {
  int i = blockIdx.x * blockDim.x + threadIdx.x;
  int e = topk_idx[i];
  int row = atomicAdd(&cursors[e], 1);
  row_of[i] = row;
  tok_of[row] = i >> 1;
}

__global__ void gather_kernel(const float* __restrict__ x, const int* __restrict__ tok_of,
                              unsigned short* __restrict__ Xp) {
  int row = blockIdx.x;
  int t = tok_of[row];
  const float4* src = (const float4*)(x + (size_t)t * H_DIM);
  ushort4* dst = (ushort4*)(Xp + (size_t)row * H_DIM);
  for (int i = threadIdx.x; i < H_DIM / 4; i += 256) {
    float4 v = src[i];
    ushort4 o;
    o.x = f2bf(v.x); o.y = f2bf(v.y); o.z = f2bf(v.z); o.w = f2bf(v.w);
    dst[i] = o;
  }
}

// ---------------- weight transpose + bf16 cast (64x64 tiles, vectorized) ----------------
// gate_up (E, H=2048, 2I=2816) fp32 -> WgT/WuT (E, I, H) bf16.
__global__ void convert_gu_kernel(const float* __restrict__ W,
                                  unsigned short* __restrict__ WgT,
                                  unsigned short* __restrict__ WuT) {
  __shared__ unsigned short t[64][72];  // pad 72: rows 144B (8B-aligned ushort4)
  int e = blockIdx.z;
  int k0 = blockIdx.y * 64;            // over H
  int n0 = blockIdx.x * 64;            // over 2I
  const float* Wp = W + (size_t)e * H_DIM * (2 * I_DIM);
  int f4 = threadIdx.x & 15, kr = threadIdx.x >> 4;
#pragma unroll
  for (int p = 0; p < 4; p++) {
    int k = kr + p * 16;
    float4 v = *(const float4*)(Wp + (size_t)(k0 + k) * (2 * I_DIM) + n0 + f4 * 4);
    t[f4 * 4 + 0][k] = f2bf(v.x);
    t[f4 * 4 + 1][k] = f2bf(v.y);
    t[f4 * 4 + 2][k] = f2bf(v.z);
    t[f4 * 4 + 3][k] = f2bf(v.w);
  }
  __syncthreads();
  unsigned short* Op;
  int nb = n0;
  if (n0 < I_DIM) Op = WgT + (size_t)e * I_DIM * H_DIM;
  else { Op = WuT + (size_t)e * I_DIM * H_DIM; nb = n0 - I_DIM; }
  int c = threadIdx.x & 15, nr = threadIdx.x >> 4;
#pragma unroll
  for (int p = 0; p < 4; p++) {
    int n = nr + p * 16;
    *(ushort4*)(Op + (size_t)(nb + n) * H_DIM + k0 + c * 4) = *(const ushort4*)&t[n][c * 4];
  }
}

// down (E, I=1408, H=2048) fp32 -> WdT (E, H, I) bf16
__global__ void convert_dn_kernel(const float* __restrict__ W,
                                  unsigned short* __restrict__ WdT) {
  __shared__ unsigned short t[64][72];
  int e = blockIdx.z;
  int k0 = blockIdx.y * 64;            // over I
  int n0 = blockIdx.x * 64;            // over H
  const float* Wp = W + (size_t)e * I_DIM * H_DIM;
  int f4 = threadIdx.x & 15, kr = threadIdx.x >> 4;
#pragma unroll
  for (int p = 0; p < 4; p++) {
    int k = kr + p * 16;
    float4 v = *(const float4*)(Wp + (size_t)(k0 + k) * H_DIM + n0 + f4 * 4);
    t[f4 * 4 + 0][k] = f2bf(v.x);
    t[f4 * 4 + 1][k] = f2bf(v.y);
    t[f4 * 4 + 2][k] = f2bf(v.z);
    t[f4 * 4 + 3][k] = f2bf(v.w);
  }
  __syncthreads();
  unsigned short* Op = WdT + (size_t)e * H_DIM * I_DIM;
  int c = threadIdx.x & 15, nr = threadIdx.x >> 4;
#pragma unroll
  for (int p = 0; p < 4; p++) {
    int n = nr + p * 16;
    *(ushort4*)(Op + (size_t)(n0 + n) * I_DIM + k0 + c * 4) = *(const ushort4*)&t[n][c * 4];
  }
}

// ---------------- GEMM1: Xp @ [Wg|Wu]^T, fused SiLU*up -> Hmid bf16 ----------------
__global__ __launch_bounds__(256, 2) void gemm1_kernel(
    const unsigned short* __restrict__ Xp,
    const unsigned short* __restrict__ WgT,
    const unsigned short* __restrict__ WuT,
    const int* __restrict__ tile_e, const int* __restrict__ tile_m0,
    const int* __restrict__ tile_end,
    unsigned short* __restrict__ Hmid) {
  int bid = blockIdx.x;
  int xcd = bid & 7, j = bid >> 3;       // j in [0,99)
  int mt, n;
  if (j < 88) {
    int c = j / 44, jj = j % 44;
    n = jj >> 2;
    mt = xcd * 9 + c * 4 + (jj & 3);
  } else {
    mt = xcd * 9 + 8;
    n = j - 88;
  }
  int e = tile_e[mt];
  if (e < 0) return;
  int m0 = tile_m0[mt];
  int row_end = tile_end[mt];
  int n0 = n * 128;

  __shared__ unsigned short sA[128 * 32];
  __shared__ unsigned short sBg[128 * 32];
  __shared__ unsigned short sBu[128 * 32];

  int tid = threadIdx.x;
  int wave = tid >> 6, lane = tid & 63;

  const unsigned short* ga[2];
  const unsigned short* ggt[2];
  const unsigned short* gut[2];
  unsigned short *la[2], *lg[2], *lu[2];
  const size_t wbase = (size_t)e * I_DIM * H_DIM;
#pragma unroll
  for (int r = 0; r < 2; r++) {
    int lin = r * 256 + tid;
    int row = lin >> 2;
    int col = (lin & 3) * 8;
    int am = m0 + row; if (am > RTOT - 1) am = RTOT - 1;
    ga[r]  = Xp  + (size_t)am * H_DIM + col;
    ggt[r] = WgT + wbase + (size_t)(n0 + row) * H_DIM + col;
    gut[r] = WuT + wbase + (size_t)(n0 + row) * H_DIM + col;
    la[r] = sA  + lin * 8;
    lg[r] = sBg + lin * 8;
    lu[r] = sBu + lin * 8;
  }

  floatx4 accg[4][4] = {};
  floatx4 accu[4][4] = {};

  const unsigned short* sAb = sA  + ((wave & 1) * 64 + (lane & 15)) * 32 + (lane >> 4) * 8;
  const unsigned short* sGb = sBg + ((wave >> 1) * 64 + (lane & 15)) * 32 + (lane >> 4) * 8;
  const unsigned short* sUb = sBu + ((wave >> 1) * 64 + (lane & 15)) * 32 + (lane >> 4) * 8;

  for (int kb = 0; kb < H_DIM / 32; kb++) {
    __syncthreads();
#pragma unroll
    for (int r = 0; r < 2; r++) {
      async16(ga[r],  la[r]); ga[r]  += 32;
      async16(ggt[r], lg[r]); ggt[r] += 32;
      async16(gut[r], lu[r]); gut[r] += 32;
    }
    __syncthreads();
    bf16x8 a[4];
#pragma unroll
    for (int mi = 0; mi < 4; mi++) a[mi] = *(const bf16x8*)(sAb + mi * 16 * 32);
#pragma unroll
    for (int ni = 0; ni < 4; ni++) {
      bf16x8 bg = *(const bf16x8*)(sGb + ni * 16 * 32);
      bf16x8 bu = *(const bf16x8*)(sUb + ni * 16 * 32);
#pragma unroll
      for (int mi = 0; mi < 4; mi++) {
        accg[mi][ni] = __builtin_amdgcn_mfma_f32_16x16x32_bf16(a[mi], bg, accg[mi][ni], 0, 0, 0);
        accu[mi][ni] = __builtin_amdgcn_mfma_f32_16x16x32_bf16(a[mi], bu, accu[mi][ni], 0, 0, 0);
      }
    }
  }

  int mrow = m0 + (wave & 1) * 64 + (lane >> 4) * 4;
  int ncol = n0 + (wave >> 1) * 64 + (lane & 15);
#pragma unroll
  for (int mi = 0; mi < 4; mi++) {
#pragma unroll
    for (int r = 0; r < 4; r++) {
      int m = mrow + mi * 16 + r;
      if (m < row_end) {
        size_t base = (size_t)m * I_DIM + ncol;
#pragma unroll
        for (int ni = 0; ni < 4; ni++) {
          float g = accg[mi][ni][r];
          float u = accu[mi][ni][r];
          float s = g / (1.0f + __expf(-g));
          Hmid[base + ni * 16] = f2bf(s * u);
        }
      }
    }
  }
}

// ---------------- GEMM2: Hmid @ Wd^T -> H2 fp32 (non-atomic) ----------------
__global__ __launch_bounds__(256, 2) void gemm2_kernel(
    const unsigned short* __restrict__ Hmid,
    const unsigned short* __restrict__ WdT,
    const int* __restrict__ tile_e, const int* __restrict__ tile_m0,
    const int* __restrict__ tile_end,
    float* __restrict__ H2) {
  int bid = blockIdx.x;
  int xcd = bid & 7, j = bid >> 3;       // j in [0,144)
  int mt, n;
  if (j < 128) {
    int c = j / 64, jj = j % 64;
    n = jj >> 2;
    mt = xcd * 9 + c * 4 + (jj & 3);
  } else {
    mt = xcd * 9 + 8;
    n = j - 128;
  }
  int e = tile_e[mt];
  if (e < 0) return;
  int m0 = tile_m0[mt];
  int row_end = tile_end[mt];
  int n0 = n * 128;

  __shared__ unsigned short sA[128 * 32];
  __shared__ unsigned short sB[128 * 32];

  int tid = threadIdx.x;
  int wave = tid >> 6, lane = tid & 63;

  const unsigned short* ga[2];
  const unsigned short* gb[2];
  unsigned short *la[2], *lb[2];
  const size_t wbase = (size_t)e * H_DIM * I_DIM;
#pragma unroll
  for (int r = 0; r < 2; r++) {
    int lin = r * 256 + tid;
    int row = lin >> 2;
    int col = (lin & 3) * 8;
    int am = m0 + row; if (am > RTOT - 1) am = RTOT - 1;
    ga[r] = Hmid + (size_t)am * I_DIM + col;
    gb[r] = WdT + wbase + (size_t)(n0 + row) * I_DIM + col;
    la[r] = sA + lin * 8;
    lb[r] = sB + lin * 8;
  }

  floatx4 acc[4][4] = {};

  const unsigned short* sAb = sA + ((wave & 1) * 64 + (lane & 15)) * 32 + (lane >> 4) * 8;
  const unsigned short* sBb = sB + ((wave >> 1) * 64 + (lane & 15)) * 32 + (lane >> 4) * 8;

  for (int kb = 0; kb < I_DIM / 32; kb++) {
    __syncthreads();
#pragma unroll
    for (int r = 0; r < 2; r++) {
      async16(ga[r], la[r]); ga[r] += 32;
      async16(gb[r], lb[r]); gb[r] += 32;
    }
    __syncthreads();
    bf16x8 a[4];
#pragma unroll
    for (int mi = 0; mi < 4; mi++) a[mi] = *(const bf16x8*)(sAb + mi * 16 * 32);
#pragma unroll
    for (int ni = 0; ni < 4; ni++) {
      bf16x8 b = *(const bf16x8*)(sBb + ni * 16 * 32);
#pragma unroll
      for (int mi = 0; mi < 4; mi++)
        acc[mi][ni] = __builtin_amdgcn_mfma_f32_16x16x32_bf16(a[mi], b, acc[mi][ni], 0, 0, 0);
    }
  }

  int mrow = m0 + (wave & 1) * 64 + (lane >> 4) * 4;
  int ncol = n0 + (wave >> 1) * 64 + (lane & 15);
#pragma unroll
  for (int mi = 0; mi < 4; mi++) {
#pragma unroll
    for (int r = 0; r < 4; r++) {
      int m = mrow + mi * 16 + r;
      if (m < row_end) {
        size_t base = (size_t)m * H_DIM + ncol;
#pragma unroll
        for (int ni = 0; ni < 4; ni++) H2[base + ni * 16] = acc[mi][ni][r];
      }
    }
  }
}

// ---------------- combine: out[t] = w0*H2[r0] + w1*H2[r1] ----------------
__global__ void combine_kernel(const float* __restrict__ H2, const int* __restrict__ row_of,
                               const float* __restrict__ topk_w, float* __restrict__ out) {
  int t = blockIdx.x >> 1;
  int part = blockIdx.x & 1;
  int c = part * 1024 + threadIdx.x * 4;
  int r0 = row_of[t * 2], r1 = row_of[t * 2 + 1];
  float w0 = topk_w[t * 2], w1 = topk_w[t * 2 + 1];
  float4 a = *(const float4*)(H2 + (size_t)r0 * H_DIM + c);
  float4 b = *(const float4*)(H2 + (size_t)r1 * H_DIM + c);
  float4 o;
  o.x = w0 * a.x + w1 * b.x;
  o.y = w0 * a.y + w1 * b.y;
  o.z = w0 * a.z + w1 * b.z;
  o.w = w0 * a.w + w1 * b.w;
  *(float4*)(out + (size_t)t * H_DIM + c) = o;
}

extern "C" void kernel_launch(void* const* d_in, const int* in_sizes, int n_in,
                              void* d_out, int out_size, void* d_ws, size_t ws_size,
                              hipStream_t stream) {
  const float* x   = (const float*)d_in[0];
  const float* rw  = (const float*)d_in[1];
  const float* wgu = (const float*)d_in[2];
  const float* wdn = (const float*)d_in[3];
  float* out = (float*)d_out;

  char* ws = (char*)d_ws;
  size_t off = 0;
  auto alloc = [&](size_t b) {
    char* p = ws + off;
    off = (off + b + 255) & ~(size_t)255;
    return p;
  };
  unsigned short* WgT  = (unsigned short*)alloc((size_t)E_NUM * I_DIM * H_DIM * 2);
  unsigned short* WuT  = (unsigned short*)alloc((size_t)E_NUM * I_DIM * H_DIM * 2);
  unsigned short* WdT  = (unsigned short*)alloc((size_t)E_NUM * H_DIM * I_DIM * 2);
  unsigned short* Xp   = (unsigned short*)alloc((size_t)RTOT * H_DIM * 2);
  unsigned short* Hmid = (unsigned short*)alloc((size_t)RTOT * I_DIM * 2);
  float* H2            = (float*)alloc((size_t)RTOT * H_DIM * 4);
  int*   topk_idx      = (int*)alloc(RTOT * 4);
  float* topk_w        = (float*)alloc(RTOT * 4);
  int*   row_of        = (int*)alloc(RTOT * 4);
  int*   tok_of        = (int*)alloc(RTOT * 4);
  int*   counts        = (int*)alloc(256);
  int*   offsets       = (int*)alloc(256);
  int*   cursors       = (int*)alloc(256);
  int*   tile_e        = (int*)alloc(128 * 4);
  int*   tile_m0       = (int*)alloc(128 * 4);
  int*   tile_end      = (int*)alloc(128 * 4);

  hipMemsetAsync(counts, 0, E_NUM * sizeof(int), stream);

  convert_gu_kernel<<<dim3(44, 32, 8), 256, 0, stream>>>(wgu, WgT, WuT);
  convert_dn_kernel<<<dim3(32, 22, 8), 256, 0, stream>>>(wdn, WdT);
  router_kernel<<<T_TOK / 4, 256, 0, stream>>>(x, rw, topk_idx, topk_w, counts);
  scan_kernel<<<1, 64, 0, stream>>>(counts, offsets, cursors, tile_e, tile_m0, tile_end);
  assign_kernel<<<RTOT / 256, 256, 0, stream>>>(topk_idx, cursors, row_of, tok_of);
  gather_kernel<<<RTOT, 256, 0, stream>>>(x, tok_of, Xp);
  gemm1_kernel<<<8 * 9 * 11, 256, 0, stream>>>(Xp, WgT, WuT, tile_e, tile_m0, tile_end, Hmid);
  gemm2_kernel<<<8 * 9 * 16, 256, 0, stream>>>(Hmid, WdT, tile_e, tile_m0, tile_end, H2);
  combine_kernel<<<T_TOK * 2, 256, 0, stream>>>(H2, row_of, topk_w, out);
}